// Round 17
// baseline (273.581 us; speedup 1.0000x reference)
//
#include <hip/hip_runtime.h>

// ---- problem constants ----
#define BB 8
#define NN 20000
#define KK 9
#define KC 576                 // KK*64
#define ROWS (BB*NN)           // 160000

// ---- workspace layout (ushort elements) ----
#define WST_ELE   36864                 // conv_w chunks [18][64][32]
#define WST2_ELE  4096                  // mlp_w chunks  [2][64][32]
#define XB_ELE    (ROWS*64)             // x in bf16, row NN-1 per batch zeroed
#define WST_OFF   0
#define WST2_OFF  36864
#define XB_OFF    40960                 // byte 81,920 (16B aligned)
// total ws use: 20,520,960 ushort = 20.5 MB

#define PROW 576                        // P row stride in ushort (1152B = 9*128B)

typedef __bf16 bf16x8 __attribute__((ext_vector_type(8)));
typedef float  f32x4  __attribute__((ext_vector_type(4)));
typedef unsigned short u16x8 __attribute__((ext_vector_type(8)));

__device__ __forceinline__ unsigned short f2bf(float f) {
    unsigned u = __builtin_bit_cast(unsigned, f);
    u += 0x7FFFu + ((u >> 16) & 1u);          // RNE
    return (unsigned short)(u >> 16);
}
__device__ __forceinline__ float bf2f(unsigned short h) {
    return __builtin_bit_cast(float, ((unsigned)h) << 16);
}
__device__ __forceinline__ float elu_f(float v) { return v > 0.0f ? v : (__expf(v) - 1.0f); }

// ---------------------------------------------------------------------------
// Prep: x -> bf16 (row NN-1 per batch zeroed), conv_w / mlp_w -> chunk order.
// ---------------------------------------------------------------------------
__global__ void __launch_bounds__(256) paiconv_prep(
        const float* __restrict__ x,       // [ROWS][64]
        const float* __restrict__ conv_w,  // [64][576]
        const float* __restrict__ mlp_w,   // [64][64]
        unsigned short* __restrict__ ws16) {
    const int tid = blockIdx.x * 256 + threadIdx.x;

    if (tid < XB_ELE / 8) {                    // 1,280,000 threads: 8 elems each
        const int e = tid * 8;
        const int r = e >> 6;                  // global row
        const int n = r % NN;                  // within-batch row
        u16x8 pk;
        if (n == NN - 1) {
            #pragma unroll
            for (int i = 0; i < 8; ++i) pk[i] = 0;   // pre-masked row
        } else {
            f32x4 lo = *(const f32x4*)(x + e);
            f32x4 hi = *(const f32x4*)(x + e + 4);
            #pragma unroll
            for (int i = 0; i < 4; ++i) { pk[i] = f2bf(lo[i]); pk[4 + i] = f2bf(hi[i]); }
        }
        *(u16x8*)(ws16 + XB_OFF + e) = pk;
    }
    if (tid < WST_ELE) {   // Wst[mch][o][kk] = conv_w[o][t*64 + c*32 + kk], mch=c*9+t
        const int kk = tid & 31, o = (tid >> 5) & 63, mch = tid >> 11;
        const int c = mch / 9, t = mch - 9 * c;
        ws16[WST_OFF + tid] = f2bf(conv_w[o * KC + t * 64 + c * 32 + kk]);
    }
    if (tid < WST2_ELE) {  // Wst2[c2][o][kk] = mlp_w[o][c2*32 + kk]
        const int kk = tid & 31, o = (tid >> 5) & 63, c2 = tid >> 11;
        ws16[WST2_OFF + tid] = f2bf(mlp_w[o * 64 + c2 * 32 + kk]);
    }
}

// ---------------------------------------------------------------------------
// Main. One wave = 16 rows. Phase 1 (lane=feature): per row, 9 single-line
// coalesced bf16-row gathers (uniform base), 9x9 mix with wave-uniform adj
// scalars (s_loads), ELU -> swizzled LDS P tile. Row groups of 4, next
// group's gathers issued before current group's compute (latency hiding).
// Phase 2: MFMA conv GEMM, A-frags from swizzled P (conflict-free), then
// residual GEMM + fused epilogue. 2 waves/block, no barriers.
//
// P swizzle: row stride 1152B (=9*128B, so every row starts at bank 0);
// 16B-unit column index col16 (0..71) is stored at col16 ^ (row&7).
// Reads (l15 = row): 8 distinct 4-bank windows across l15&7 -> 2-way = free.
// ---------------------------------------------------------------------------
__global__ void __launch_bounds__(128) paiconv_main(
        const int*   __restrict__ nidx,     // [ROWS][9] (int32 on device)
        const float* __restrict__ adj,      // [NN][81] fp32
        const float* __restrict__ conv_b,   // [64]
        const float* __restrict__ mlp_b,    // [64]
        const unsigned short* __restrict__ ws16,
        float* __restrict__ out) {          // [ROWS][64]
    __shared__ unsigned short P[2][16 * PROW];   // 36,864 B

    const int tx   = threadIdx.x;
    const int lane = tx & 63;
    const int l15  = lane & 15;
    const int q    = lane >> 4;
    const int wave = __builtin_amdgcn_readfirstlane(tx >> 6);
    const int batch = blockIdx.x & 7;
    const int chunk = blockIdx.x >> 3;          // 0..624
    const int n0    = chunk * 32 + wave * 16;   // within-batch base row (20000 = 625*32)
    const int rowbase = batch * NN + n0;

    const unsigned short* Wst  = ws16 + WST_OFF;
    const unsigned short* Wst2 = ws16 + WST2_OFF;
    const unsigned short* XB   = ws16 + XB_OFF;
    const unsigned short* XBb  = XB + (size_t)batch * NN * 64;   // batch slice
    unsigned short* Pw = &P[wave][0];

    // write column unit for this lane (before row-xor): t*8 + (lane>>3)
    const int wcol_lane = lane >> 3;
    const int wsub      = lane & 7;

    // ---- phase 1: pipelined row groups of 4 ----
    float vf[4][KK];
    #pragma unroll
    for (int rr = 0; rr < 4; ++rr) {
        const int grow = rowbase + rr;
        #pragma unroll
        for (int k = 0; k < KK; ++k) {
            const int idx = nidx[grow * KK + k];              // uniform -> s_load
            vf[rr][k] = bf2f(XBb[idx * 64 + lane]);           // 1 line / instr
        }
    }

    #pragma unroll
    for (int rg = 0; rg < 4; ++rg) {
        float vn[4][KK];
        if (rg < 3) {
            #pragma unroll
            for (int rr = 0; rr < 4; ++rr) {
                const int grow = rowbase + (rg + 1) * 4 + rr;
                #pragma unroll
                for (int k = 0; k < KK; ++k) {
                    const int idx = nidx[grow * KK + k];
                    vn[rr][k] = bf2f(XBb[idx * 64 + lane]);
                }
            }
        }
        #pragma unroll
        for (int rr = 0; rr < 4; ++rr) {
            const int r = rg * 4 + rr;
            const float* adjrow = adj + (size_t)(n0 + r) * 81;  // uniform -> s_loads
            float m[KK] = {0.f,0.f,0.f,0.f,0.f,0.f,0.f,0.f,0.f};
            #pragma unroll
            for (int k = 0; k < KK; ++k) {
                const float a0 = vf[rr][k];
                #pragma unroll
                for (int t = 0; t < KK; ++t)
                    m[t] = __builtin_fmaf(adjrow[k * 9 + t], a0, m[t]);
            }
            const int rx = r & 7;
            #pragma unroll
            for (int t = 0; t < KK; ++t) {
                const int colu = (t * 8 + wcol_lane) ^ rx;      // swizzled 16B unit
                Pw[r * PROW + colu * 8 + wsub] = f2bf(elu_f(m[t]));
            }
        }
        if (rg < 3) {
            #pragma unroll
            for (int rr = 0; rr < 4; ++rr)
                #pragma unroll
                for (int k = 0; k < KK; ++k) vf[rr][k] = vn[rr][k];
        }
    }

    // ---- phase 2: conv GEMM, A-frags from swizzled P ----
    f32x4 acc[4];    // conv accumulators (o-tiles of 16)
    f32x4 acc2[4];   // residual accumulators
    #pragma unroll
    for (int ot = 0; ot < 4; ++ot) { acc[ot] = (f32x4)0.0f; acc2[ot] = (f32x4)0.0f; }

    const int lx = l15 & 7;
    #pragma unroll
    for (int c = 0; c < 2; ++c) {
        #pragma unroll
        for (int t = 0; t < KK; ++t) {
            const int colu = (t * 8 + c * 4 + q) ^ lx;
            const u16x8* ap = (const u16x8*)(Pw + l15 * PROW + colu * 8);
            bf16x8 afrag = __builtin_bit_cast(bf16x8, *ap);
            const int mch = c * 9 + t;
            #pragma unroll
            for (int ot = 0; ot < 4; ++ot) {
                const u16x8* wp = (const u16x8*)(Wst + mch * 2048 + (ot * 16 + l15) * 32 + q * 8);
                bf16x8 bfrag = __builtin_bit_cast(bf16x8, *wp);
                acc[ot] = __builtin_amdgcn_mfma_f32_16x16x32_bf16(afrag, bfrag, acc[ot], 0, 0, 0);
            }
        }
    }

    // ---- residual GEMM: xb(row pre-masked) @ mlp_w^T ----
    #pragma unroll
    for (int c2 = 0; c2 < 2; ++c2) {
        bf16x8 a2 = *(const bf16x8*)(XB + (size_t)(rowbase + l15) * 64 + c2 * 32 + q * 8);
        #pragma unroll
        for (int ot = 0; ot < 4; ++ot) {
            const u16x8* wp = (const u16x8*)(Wst2 + c2 * 2048 + (ot * 16 + l15) * 32 + q * 8);
            bf16x8 b2 = __builtin_bit_cast(bf16x8, *wp);
            acc2[ot] = __builtin_amdgcn_mfma_f32_16x16x32_bf16(a2, b2, acc2[ot], 0, 0, 0);
        }
    }

    // ---- epilogue: elu(conv+cb)*mask + res + mb -> LDS transpose (reuse P) ----
    float* smf = (float*)Pw;                     // 16 x 68 f32 fits in P region
    #pragma unroll
    for (int ot = 0; ot < 4; ++ot) {
        const int o = ot * 16 + l15;
        const float cb = conv_b[o];
        const float mb = mlp_b[o];
        #pragma unroll
        for (int i = 0; i < 4; ++i) {
            const int rr = 4 * q + i;                    // C/D: row = 4*(lane>>4)+reg
            float f = elu_f(acc[ot][i] + cb);
            if (n0 + rr == NN - 1) f = 0.0f;             // output mask
            f += acc2[ot][i] + mb;
            smf[rr * 68 + o] = f;
        }
    }
    #pragma unroll
    for (int p = 0; p < 4; ++p) {
        const int r = p * 4 + q;
        f32x4 vv = *(const f32x4*)&smf[r * 68 + l15 * 4];
        *(f32x4*)(out + (size_t)(rowbase + r) * 64 + l15 * 4) = vv;
    }
}

extern "C" void kernel_launch(void* const* d_in, const int* in_sizes, int n_in,
                              void* d_out, int out_size, void* d_ws, size_t ws_size,
                              hipStream_t stream) {
    const float* x      = (const float*)d_in[0];
    const int*   nidx   = (const int*)  d_in[1];
    const float* adj    = (const float*)d_in[2];
    const float* conv_w = (const float*)d_in[3];
    const float* conv_b = (const float*)d_in[4];
    const float* mlp_w  = (const float*)d_in[5];
    const float* mlp_b  = (const float*)d_in[6];
    unsigned short* ws16 = (unsigned short*)d_ws;
    float* out = (float*)d_out;

    const int prep_blocks = (XB_ELE / 8) / 256;           // 5000
    paiconv_prep<<<prep_blocks, 256, 0, stream>>>(x, conv_w, mlp_w, ws16);

    const int main_blocks = 8 * 625;                      // batch = bid&7, chunk = bid>>3
    paiconv_main<<<main_blocks, 128, 0, stream>>>(nidx, adj, conv_b, mlp_b, ws16, out);
}